// Round 2
// baseline (4056.363 us; speedup 1.0000x reference)
//
#include <hip/hip_runtime.h>
#include <stdint.h>

// ---------------------------------------------------------------------------
// Edgewise (eSCN SO(2) conv block), MI355X gfx950.
// Edge-CHUNKED pipeline (chunk size adapted to ws_size at runtime; ws_size is
// constant across calls so the launch sequence is deterministic):
//   once: transpose weights -> bf16 (N,K)
//   per chunk of CH edges:
//     radial MLP (3 MFMA GEMMs + LN/SiLU)
//     wigner fwd (gather + per-edge matmul + x_rad scale) -> msgS bf16
//     conv1: 5 MFMA GEMMs ; gate+recombine -> msg2 bf16
//     conv2: 5 MFMA GEMMs ; recombine2 (+envelope) -> msg3
//     wigner inv + atomic scatter into d_out (f32)
// ---------------------------------------------------------------------------

#define E_NUM   20000

typedef uint16_t u16;
typedef __bf16  bf16x8 __attribute__((ext_vector_type(8)));
typedef float   f32x4  __attribute__((ext_vector_type(4)));
typedef uint16_t u16x8 __attribute__((ext_vector_type(8)));

__device__ __forceinline__ float bf2f(u16 h){
  uint32_t u = ((uint32_t)h) << 16;
  return __builtin_bit_cast(float, u);
}
__device__ __forceinline__ u16 f2bf(float f){
  uint32_t u = __builtin_bit_cast(uint32_t, f);
  u += 0x7fffu + ((u >> 16) & 1u);
  return (u16)(u >> 16);
}
__device__ __forceinline__ float sigm(float x){ return 1.f / (1.f + __expf(-x)); }

// --------------------------- weight transpose ------------------------------
// in: f32 (K,N) row-major  ->  out: bf16 (N,K) row-major.  K,N multiples of 32.
__global__ void k_transpose_w(const float* __restrict__ in, u16* __restrict__ out,
                              int K, int N){
  __shared__ float t[32][33];
  int nb = blockIdx.x * 32, kb = blockIdx.y * 32;
  int tx = threadIdx.x & 31, ty = threadIdx.x >> 5;   // 32x8
  for (int i = ty; i < 32; i += 8)
    t[i][tx] = in[(size_t)(kb + i) * N + (nb + tx)];
  __syncthreads();
  for (int i = ty; i < 32; i += 8)
    out[(size_t)(nb + i) * K + (kb + tx)] = f2bf(t[tx][i]);
}

__global__ void k_f2bf(const float* __restrict__ in, u16* __restrict__ out, int n){
  int i = blockIdx.x * 256 + threadIdx.x;
  int stride = gridDim.x * 256;
  for (; i < n; i += stride) out[i] = f2bf(in[i]);
}

// ------------------------------- GEMM --------------------------------------
// C(M,N) = A(M,K) @ B^T  with B given as (N,K) bf16, k-contiguous both sides.
// 128x128 tile, BK=32, 4 waves (2x2), each wave 64x64 via 4x4 MFMA 16x16x32.
// Optional bias[N]; stores f32 (Cb==null) or bf16 (Cb!=null).
__global__ __launch_bounds__(256) void k_gemm_bt(
    const u16* __restrict__ A, int lda,
    const u16* __restrict__ B,
    const float* __restrict__ bias,
    float* __restrict__ Cf, u16* __restrict__ Cb, int ldc,
    int M, int N, int K)
{
  __shared__ u16 As[128][40];   // row stride 80B = 5*16B: aligned b128, ~2-way banks
  __shared__ u16 Bs[128][40];
  const int tid  = threadIdx.x;
  const int lane = tid & 63;
  const int wave = tid >> 6;
  const int wm = wave >> 1, wn = wave & 1;
  const int fr = lane & 15, fq = lane >> 4;
  const int bn = blockIdx.x, bm = blockIdx.y;
  const int row0 = bm * 128;

  f32x4 acc[4][4];
  #pragma unroll
  for (int i = 0; i < 4; ++i)
    #pragma unroll
    for (int j = 0; j < 4; ++j) acc[i][j] = (f32x4){0.f, 0.f, 0.f, 0.f};

  const int r0 = tid >> 2;          // 0..63
  const int c0 = (tid & 3) * 8;     // 0,8,16,24

  for (int k0 = 0; k0 < K; k0 += 32){
    #pragma unroll
    for (int h = 0; h < 2; ++h){
      int r = r0 + h * 64;
      int gr = row0 + r;
      u16x8 va = {0,0,0,0,0,0,0,0};
      if (gr < M) va = *(const u16x8*)(A + (size_t)gr * lda + k0 + c0);
      *(u16x8*)(&As[r][c0]) = va;
      int gn = bn * 128 + r;        // N is always a multiple of 128
      u16x8 vb = *(const u16x8*)(B + (size_t)gn * K + k0 + c0);
      *(u16x8*)(&Bs[r][c0]) = vb;
    }
    __syncthreads();
    bf16x8 af[4], bfv[4];
    #pragma unroll
    for (int mi = 0; mi < 4; ++mi)
      af[mi] = __builtin_bit_cast(bf16x8, *(const u16x8*)(&As[wm*64 + mi*16 + fr][fq*8]));
    #pragma unroll
    for (int ni = 0; ni < 4; ++ni)
      bfv[ni] = __builtin_bit_cast(bf16x8, *(const u16x8*)(&Bs[wn*64 + ni*16 + fr][fq*8]));
    #pragma unroll
    for (int mi = 0; mi < 4; ++mi)
      #pragma unroll
      for (int ni = 0; ni < 4; ++ni)
        acc[mi][ni] = __builtin_amdgcn_mfma_f32_16x16x32_bf16(af[mi], bfv[ni], acc[mi][ni], 0, 0, 0);
    __syncthreads();
  }

  #pragma unroll
  for (int ni = 0; ni < 4; ++ni){
    int col = bn * 128 + wn * 64 + ni * 16 + fr;
    float bv = bias ? bias[col] : 0.f;
    #pragma unroll
    for (int mi = 0; mi < 4; ++mi){
      #pragma unroll
      for (int i = 0; i < 4; ++i){
        int row = row0 + wm * 64 + mi * 16 + fq * 4 + i;
        if (row < M){
          float v = acc[mi][ni][i] + bv;
          if (Cb) Cb[(size_t)row * ldc + col] = f2bf(v);
          else    Cf[(size_t)row * ldc + col] = v;
        }
      }
    }
  }
}

// --------------------------- LayerNorm + SiLU ------------------------------
__global__ __launch_bounds__(256) void k_ln_silu(
    const float* __restrict__ in, const float* __restrict__ sc,
    const float* __restrict__ bb, u16* __restrict__ out)
{
  int e = blockIdx.x, t = threadIdx.x;
  float v = in[(size_t)e * 256 + t];
  float s1 = v, s2 = v * v;
  #pragma unroll
  for (int off = 32; off > 0; off >>= 1){
    s1 += __shfl_down(s1, off);
    s2 += __shfl_down(s2, off);
  }
  __shared__ float r1[4], r2[4];
  if ((t & 63) == 0){ r1[t >> 6] = s1; r2[t >> 6] = s2; }
  __syncthreads();
  float S1 = r1[0] + r1[1] + r1[2] + r1[3];
  float S2 = r2[0] + r2[1] + r2[2] + r2[3];
  float mu  = S1 * (1.f / 256.f);
  float var = S2 * (1.f / 256.f) - mu * mu;
  float nv = (v - mu) * rsqrtf(var + 1e-5f) * sc[t] + bb[t];
  out[(size_t)e * 256 + t] = f2bf(nv * sigm(nv));
}

// --------------------- Wigner forward (gather+scale) -----------------------
// local edge el in [0,cm); global edge = e0 + el.
__global__ __launch_bounds__(256) void k_wig_fwd(
    const float* __restrict__ x, const int* __restrict__ eidx,
    const float* __restrict__ wig, const u16* __restrict__ xrad,
    u16* __restrict__ msgS, int e0)
{
  int el = blockIdx.x, c = threadIdx.x;
  int eg = e0 + el;
  int node = eidx[(c < 128 ? 0 : E_NUM) + eg];
  const float* xs = x + (size_t)node * 49 * 128 + (c & 127);
  float xv[49];
  #pragma unroll
  for (int j = 0; j < 49; ++j) xv[j] = xs[(size_t)j * 128];
  const float* w = wig + (size_t)eg * 29 * 49;   // uniform per block -> s_loads
  float acc[29];
  #pragma unroll
  for (int m = 0; m < 29; ++m){
    float a = 0.f;
    #pragma unroll
    for (int j = 0; j < 49; ++j) a = fmaf(w[m * 49 + j], xv[j], a);
    acc[m] = a;
  }
  const u16* xr = xrad + (size_t)el * 4608 + c;
  u16* o = msgS + (size_t)el * 7424 + c;
  #pragma unroll
  for (int m = 0; m < 29; ++m){
    int rr = (m < 13) ? m : (m < 24 ? m - 6 : m - 11);
    o[m * 256] = f2bf(acc[m] * bf2f(xr[rr * 256]));
  }
}

// ------------------------ gate + recombine (conv1) -------------------------
__global__ __launch_bounds__(128) void k_gate(
    const u16* __restrict__ c1m0, const u16* __restrict__ y10, const u16* __restrict__ y11,
    const u16* __restrict__ y20, const u16* __restrict__ y21, u16* __restrict__ msg2)
{
  int e = blockIdx.x, c = threadIdx.x;
  __shared__ float g[768];
  const u16* gp = c1m0 + (size_t)e * 1664;
  for (int i = c; i < 768; i += 128) g[i] = sigm(bf2f(gp[i]));
  __syncthreads();
  const u16* x0 = gp + 768;
  u16* o = msg2 + (size_t)e * 3712;
  { float v = bf2f(x0[c]); o[c] = f2bf(v * sigm(v)); }       // row 0: silu, ungated
  #pragma unroll
  for (int r = 1; r < 7; ++r)
    o[r * 128 + c] = f2bf(bf2f(x0[r * 128 + c]) * g[(r - 1) * 128 + c]);
  const u16* a0 = y10 + (size_t)e * 1536;
  const u16* a1 = y11 + (size_t)e * 1536;
  #pragma unroll
  for (int k = 0; k < 6; ++k){
    float orr = bf2f(a0[k * 128 + c]) - bf2f(a1[768 + k * 128 + c]);
    float oii = bf2f(a1[k * 128 + c]) + bf2f(a0[768 + k * 128 + c]);
    float gv = g[k * 128 + c];
    o[(7 + k)  * 128 + c] = f2bf(orr * gv);
    o[(13 + k) * 128 + c] = f2bf(oii * gv);
  }
  const u16* b0 = y20 + (size_t)e * 1280;
  const u16* b1 = y21 + (size_t)e * 1280;
  #pragma unroll
  for (int k = 0; k < 5; ++k){
    float orr = bf2f(b0[k * 128 + c]) - bf2f(b1[640 + k * 128 + c]);
    float oii = bf2f(b1[k * 128 + c]) + bf2f(b0[640 + k * 128 + c]);
    float gv = g[(1 + k) * 128 + c];
    o[(19 + k) * 128 + c] = f2bf(orr * gv);
    o[(24 + k) * 128 + c] = f2bf(oii * gv);
  }
}

// --------------------- recombine2 + envelope (conv2) -----------------------
__global__ __launch_bounds__(128) void k_recomb2(
    const u16* __restrict__ m3x0, const u16* __restrict__ z10, const u16* __restrict__ z11,
    const u16* __restrict__ z20, const u16* __restrict__ z21, const float* __restrict__ env,
    u16* __restrict__ msg3)
{
  int e = blockIdx.x, c = threadIdx.x;
  float ev = env[e];
  const u16* x0 = m3x0 + (size_t)e * 896;
  u16* o = msg3 + (size_t)e * 3712;
  #pragma unroll
  for (int r = 0; r < 7; ++r) o[r * 128 + c] = f2bf(bf2f(x0[r * 128 + c]) * ev);
  const u16* a0 = z10 + (size_t)e * 1536;
  const u16* a1 = z11 + (size_t)e * 1536;
  #pragma unroll
  for (int k = 0; k < 6; ++k){
    float orr = bf2f(a0[k * 128 + c]) - bf2f(a1[768 + k * 128 + c]);
    float oii = bf2f(a1[k * 128 + c]) + bf2f(a0[768 + k * 128 + c]);
    o[(7 + k)  * 128 + c] = f2bf(orr * ev);
    o[(13 + k) * 128 + c] = f2bf(oii * ev);
  }
  const u16* b0 = z20 + (size_t)e * 1280;
  const u16* b1 = z21 + (size_t)e * 1280;
  #pragma unroll
  for (int k = 0; k < 5; ++k){
    float orr = bf2f(b0[k * 128 + c]) - bf2f(b1[640 + k * 128 + c]);
    float oii = bf2f(b1[k * 128 + c]) + bf2f(b0[640 + k * 128 + c]);
    o[(19 + k) * 128 + c] = f2bf(orr * ev);
    o[(24 + k) * 128 + c] = f2bf(oii * ev);
  }
}

// -------------------- Wigner inverse + scatter-add -------------------------
__global__ __launch_bounds__(128) void k_wig_inv(
    const u16* __restrict__ msg3, const float* __restrict__ winv,
    const int* __restrict__ eidx, float* __restrict__ out, int e0)
{
  int el = blockIdx.x, c = threadIdx.x;
  int eg = e0 + el;
  const u16* mp = msg3 + (size_t)el * 3712 + c;
  float vm[29];
  #pragma unroll
  for (int m = 0; m < 29; ++m) vm[m] = bf2f(mp[m * 128]);
  const float* w = winv + (size_t)eg * 49 * 29;   // uniform -> s_loads
  int dst = eidx[E_NUM + eg];
  float* op = out + (size_t)dst * 49 * 128 + c;
  for (int j = 0; j < 49; ++j){
    float a = 0.f;
    #pragma unroll
    for (int m = 0; m < 29; ++m) a = fmaf(w[j * 29 + m], vm[m], a);
    atomicAdd(op + (size_t)j * 128, a);
  }
}

// ---------------------------------------------------------------------------
extern "C" void kernel_launch(void* const* d_in, const int* in_sizes, int n_in,
                              void* d_out, int out_size, void* d_ws, size_t ws_size,
                              hipStream_t stream)
{
  (void)in_sizes; (void)n_in;
  const float* x       = (const float*)d_in[0];
  const float* x_edge  = (const float*)d_in[1];
  const int*   eidx    = (const int*)d_in[3];
  const float* wig     = (const float*)d_in[4];
  const float* wig_inv = (const float*)d_in[5];
  const float* env     = (const float*)d_in[6];
  const float* rad_w0  = (const float*)d_in[7];
  const float* rad_b0  = (const float*)d_in[8];
  const float* ln0_s   = (const float*)d_in[9];
  const float* ln0_b   = (const float*)d_in[10];
  const float* rad_w1  = (const float*)d_in[11];
  const float* rad_b1  = (const float*)d_in[12];
  const float* ln1_s   = (const float*)d_in[13];
  const float* ln1_b   = (const float*)d_in[14];
  const float* rad_w2  = (const float*)d_in[15];
  const float* rad_b2  = (const float*)d_in[16];
  const float* c1w0    = (const float*)d_in[17];
  const float* c1b0    = (const float*)d_in[18];
  const float* c1w1    = (const float*)d_in[19];
  const float* c1w2    = (const float*)d_in[20];
  const float* c2w0    = (const float*)d_in[21];
  const float* c2b0    = (const float*)d_in[22];
  const float* c2w1    = (const float*)d_in[23];
  const float* c2w2    = (const float*)d_in[24];
  float* out = (float*)d_out;

  char* base = (char*)d_ws;
  size_t off = 0;
  auto alloc = [&](size_t bytes) -> char* {
    off = (off + 255) & ~(size_t)255;
    char* r = base + off;
    off += bytes;
    return r;
  };

  // ---- fixed area: transposed bf16 weights (~22.2 MB) ----
  u16* wtR0  = (u16*)alloc((size_t)256  * 128  * 2);
  u16* wtR1  = (u16*)alloc((size_t)256  * 256  * 2);
  u16* wtR2  = (u16*)alloc((size_t)4608 * 256  * 2);
  u16* wtC10 = (u16*)alloc((size_t)1664 * 1792 * 2);
  u16* wtC11 = (u16*)alloc((size_t)1536 * 1536 * 2);
  u16* wtC12 = (u16*)alloc((size_t)1280 * 1280 * 2);
  u16* wtC20 = (u16*)alloc((size_t)896  * 896  * 2);
  u16* wtC21 = (u16*)alloc((size_t)1536 * 768  * 2);
  u16* wtC22 = (u16*)alloc((size_t)1280 * 640  * 2);

  // ---- chunk size from remaining workspace (40,960 B per edge) ----
  size_t fixed_end = (off + 65536) & ~(size_t)65535;
  size_t avail = (ws_size > fixed_end + (1u << 20)) ? (ws_size - fixed_end - (1u << 20)) : 0;
  int CH = (int)(avail / 40960);
  if (CH > 5000) CH = 5000;
  CH &= ~63;
  if (CH < 64) CH = 64;       // nothing sane left; smallest viable

  off = fixed_end;
  const size_t C = (size_t)CH;
  u16*   xe   = (u16*)alloc(C * 128 * 2);
  float* tmp  = (float*)alloc(C * 256 * 4);
  u16*   h0   = (u16*)alloc(C * 256 * 2);
  u16*   h1   = (u16*)alloc(C * 256 * 2);
  u16* region1 = (u16*)alloc(C * 4608 * 2);   // xrad -> msg2
  u16* region2 = (u16*)alloc(C * 7424 * 2);   // msgS -> conv2 outs
  u16* region3 = (u16*)alloc(C * 7296 * 2);   // conv1 outs -> msg3
  u16* xrad = region1;
  u16* msg2 = region1;
  u16* msgS = region2;
  u16* m3x0 = region2;                 // (C,896)
  u16* z10  = region2 + C * 896;       // (C,1536)
  u16* z11  = region2 + C * 2432;      // (C,1536)
  u16* z20  = region2 + C * 3968;      // (C,1280)
  u16* z21  = region2 + C * 5248;      // (C,1280)
  u16* c1m0b = region3;                // (C,1664)
  u16* y10   = region3 + C * 1664;     // (C,1536)
  u16* y11   = region3 + C * 3200;     // (C,1536)
  u16* y20   = region3 + C * 4736;     // (C,1280)
  u16* y21   = region3 + C * 6016;     // (C,1280)
  u16* msg3  = region3;                // (C,3712)

  hipMemsetAsync(d_out, 0, (size_t)out_size * sizeof(float), stream);

  auto tw = [&](const float* in, u16* o, int K, int N){
    k_transpose_w<<<dim3(N / 32, K / 32), 256, 0, stream>>>(in, o, K, N);
  };
  tw(rad_w0, wtR0, 128, 256);
  tw(rad_w1, wtR1, 256, 256);
  tw(rad_w2, wtR2, 256, 4608);
  tw(c1w0, wtC10, 1792, 1664);
  tw(c1w1, wtC11, 1536, 1536);
  tw(c1w2, wtC12, 1280, 1280);
  tw(c2w0, wtC20, 896, 896);
  tw(c2w1, wtC21, 768, 1536);
  tw(c2w2, wtC22, 640, 1280);

  auto gemm = [&](const u16* A, int lda, const u16* B, const float* bias,
                  float* Cf, u16* Cb, int ldc, int M, int N, int K){
    k_gemm_bt<<<dim3(N / 128, (M + 127) / 128), 256, 0, stream>>>(
        A, lda, B, bias, Cf, Cb, ldc, M, N, K);
  };

  for (int e0 = 0; e0 < E_NUM; e0 += CH){
    int cm = E_NUM - e0 < CH ? E_NUM - e0 : CH;

    k_f2bf<<<(cm * 128 + 255) / 256, 256, 0, stream>>>(x_edge + (size_t)e0 * 128, xe, cm * 128);

    // radial MLP
    gemm(xe, 128, wtR0, rad_b0, tmp, nullptr, 256, cm, 256, 128);
    k_ln_silu<<<cm, 256, 0, stream>>>(tmp, ln0_s, ln0_b, h0);
    gemm(h0, 256, wtR1, rad_b1, tmp, nullptr, 256, cm, 256, 256);
    k_ln_silu<<<cm, 256, 0, stream>>>(tmp, ln1_s, ln1_b, h1);
    gemm(h1, 256, wtR2, rad_b2, nullptr, xrad, 4608, cm, 4608, 256);

    // wigner forward + gather + radial scale
    k_wig_fwd<<<cm, 256, 0, stream>>>(x, eidx, wig, xrad, msgS, e0);

    // conv1
    gemm(msgS,        7424, wtC10, c1b0,    nullptr, c1m0b, 1664, cm, 1664, 1792);
    gemm(msgS + 1792, 7424, wtC11, nullptr, nullptr, y10,  1536, cm, 1536, 1536);
    gemm(msgS + 3328, 7424, wtC11, nullptr, nullptr, y11,  1536, cm, 1536, 1536);
    gemm(msgS + 4864, 7424, wtC12, nullptr, nullptr, y20,  1280, cm, 1280, 1280);
    gemm(msgS + 6144, 7424, wtC12, nullptr, nullptr, y21,  1280, cm, 1280, 1280);

    k_gate<<<cm, 128, 0, stream>>>(c1m0b, y10, y11, y20, y21, msg2);

    // conv2
    gemm(msg2,        3712, wtC20, c2b0,    nullptr, m3x0, 896,  cm, 896,  896);
    gemm(msg2 + 896,  3712, wtC21, nullptr, nullptr, z10, 1536, cm, 1536, 768);
    gemm(msg2 + 1664, 3712, wtC21, nullptr, nullptr, z11, 1536, cm, 1536, 768);
    gemm(msg2 + 2432, 3712, wtC22, nullptr, nullptr, z20, 1280, cm, 1280, 640);
    gemm(msg2 + 3072, 3712, wtC22, nullptr, nullptr, z21, 1280, cm, 1280, 640);

    k_recomb2<<<cm, 128, 0, stream>>>(m3x0, z10, z11, z20, z21, env + e0, msg3);

    // wigner inverse + scatter
    k_wig_inv<<<cm, 128, 0, stream>>>(msg3, wig_inv, eidx, out, e0);
  }
}

// Round 3
// 4005.931 us; speedup vs baseline: 1.0126x; 1.0126x over previous
//
#include <hip/hip_runtime.h>
#include <stdint.h>

// ---------------------------------------------------------------------------
// Edgewise (eSCN SO(2) conv block), MI355X gfx950.
// Round 3: GEMM upgraded to m97 structure (global_load_lds width-16 staging,
// linear LDS + granule XOR swizzle with pre-swizzled global source);
// wig_fwd j-blocked for load-latency hiding; wig_inv 256 threads.
// ---------------------------------------------------------------------------

#define E_NUM   20000

typedef uint16_t u16;
typedef __bf16  bf16x8 __attribute__((ext_vector_type(8)));
typedef float   f32x4  __attribute__((ext_vector_type(4)));
typedef uint16_t u16x8 __attribute__((ext_vector_type(8)));

__device__ __forceinline__ float bf2f(u16 h){
  uint32_t u = ((uint32_t)h) << 16;
  return __builtin_bit_cast(float, u);
}
__device__ __forceinline__ u16 f2bf(float f){
  uint32_t u = __builtin_bit_cast(uint32_t, f);
  u += 0x7fffu + ((u >> 16) & 1u);
  return (u16)(u >> 16);
}
__device__ __forceinline__ float sigm(float x){ return 1.f / (1.f + __expf(-x)); }

__device__ __forceinline__ void gload16(const void* g, void* l){
  __builtin_amdgcn_global_load_lds(
      (const __attribute__((address_space(1))) void*)g,
      (__attribute__((address_space(3))) void*)l, 16, 0, 0);
}

// --------------------------- weight transpose ------------------------------
__global__ void k_transpose_w(const float* __restrict__ in, u16* __restrict__ out,
                              int K, int N){
  __shared__ float t[32][33];
  int nb = blockIdx.x * 32, kb = blockIdx.y * 32;
  int tx = threadIdx.x & 31, ty = threadIdx.x >> 5;   // 32x8
  for (int i = ty; i < 32; i += 8)
    t[i][tx] = in[(size_t)(kb + i) * N + (nb + tx)];
  __syncthreads();
  for (int i = ty; i < 32; i += 8)
    out[(size_t)(nb + i) * K + (kb + tx)] = f2bf(t[tx][i]);
}

__global__ void k_f2bf(const float* __restrict__ in, u16* __restrict__ out, int n){
  int i = blockIdx.x * 256 + threadIdx.x;
  int stride = gridDim.x * 256;
  for (; i < n; i += stride) out[i] = f2bf(in[i]);
}

// ------------------------------- GEMM --------------------------------------
// C(M,N) = A(M,K) @ B^T, B given (N,K) bf16, both k-contiguous.
// m97 structure: 128x128 tile, BK=32, global_load_lds dwordx4 staging into
// linear LDS [128][32] u16 with granule swizzle g^=((row>>1)&3) applied by
// pre-swizzling the per-lane GLOBAL source (rule #21: linear dest +
// inverse-swizzled source + swizzled read).
__global__ __launch_bounds__(256) void k_gemm_bt(
    const u16* __restrict__ A, int lda,
    const u16* __restrict__ B,
    const float* __restrict__ bias,
    float* __restrict__ Cf, u16* __restrict__ Cb, int ldc,
    int M, int N, int K)
{
  __shared__ u16 As[128 * 32];
  __shared__ u16 Bs[128 * 32];
  const int tid  = threadIdx.x;
  const int lane = tid & 63;
  const int wave = tid >> 6;
  const int wm = wave >> 1, wn = wave & 1;
  const int fr = lane & 15, fq = lane >> 4;
  const int bn = blockIdx.x, bm = blockIdx.y;
  const int row0 = bm * 128;

  // ---- staging source/dest (per-lane, computed once) ----
  // load covers 16 LDS rows: lane i -> LDS row rb+(i>>2), granule (i&3).
  // LDS[r][g] holds global granule g^((r>>1)&3) of row r.
  const int lr  = lane >> 2;          // 0..15 row within load
  const int lg  = lane & 3;           // LDS granule
  const int rA0 = wave * 32 + lr;     // LDS rows for the wave's two A loads
  const int rA1 = rA0 + 16;
  const int g0  = lg ^ ((rA0 >> 1) & 3);   // swizzled source granule
  const int g1  = lg ^ ((rA1 >> 1) & 3);
  int gra0 = row0 + rA0; if (gra0 > M - 1) gra0 = M - 1;
  int gra1 = row0 + rA1; if (gra1 > M - 1) gra1 = M - 1;
  const u16* aS0 = A + (size_t)gra0 * lda + g0 * 8;
  const u16* aS1 = A + (size_t)gra1 * lda + g1 * 8;
  const u16* bS0 = B + (size_t)(bn * 128 + rA0) * K + g0 * 8;
  const u16* bS1 = B + (size_t)(bn * 128 + rA1) * K + g1 * 8;
  u16* aD0 = As + (wave * 32) * 32;        // wave-uniform LDS bases
  u16* aD1 = As + (wave * 32 + 16) * 32;
  u16* bD0 = Bs + (wave * 32) * 32;
  u16* bD1 = Bs + (wave * 32 + 16) * 32;

  // ---- fragment LDS read addresses (fixed across k-steps) ----
  const u16* afp[4]; const u16* bfp[4];
  #pragma unroll
  for (int mi = 0; mi < 4; ++mi){
    int r = wm * 64 + mi * 16 + fr;
    afp[mi] = As + r * 32 + (fq ^ ((r >> 1) & 3)) * 8;
  }
  #pragma unroll
  for (int ni = 0; ni < 4; ++ni){
    int r = wn * 64 + ni * 16 + fr;
    bfp[ni] = Bs + r * 32 + (fq ^ ((r >> 1) & 3)) * 8;
  }

  f32x4 acc[4][4];
  #pragma unroll
  for (int i = 0; i < 4; ++i)
    #pragma unroll
    for (int j = 0; j < 4; ++j) acc[i][j] = (f32x4){0.f, 0.f, 0.f, 0.f};

  for (int k0 = 0; k0 < K; k0 += 32){
    gload16(aS0 + k0, aD0);
    gload16(aS1 + k0, aD1);
    gload16(bS0 + k0, bD0);
    gload16(bS1 + k0, bD1);
    __syncthreads();                 // drains vmcnt(0): LDS tile ready
    bf16x8 af[4], bfv[4];
    #pragma unroll
    for (int mi = 0; mi < 4; ++mi)
      af[mi] = __builtin_bit_cast(bf16x8, *(const u16x8*)afp[mi]);
    #pragma unroll
    for (int ni = 0; ni < 4; ++ni)
      bfv[ni] = __builtin_bit_cast(bf16x8, *(const u16x8*)bfp[ni]);
    #pragma unroll
    for (int mi = 0; mi < 4; ++mi)
      #pragma unroll
      for (int ni = 0; ni < 4; ++ni)
        acc[mi][ni] = __builtin_amdgcn_mfma_f32_16x16x32_bf16(af[mi], bfv[ni], acc[mi][ni], 0, 0, 0);
    __syncthreads();                 // ds_reads done before next stage
  }

  #pragma unroll
  for (int ni = 0; ni < 4; ++ni){
    int col = bn * 128 + wn * 64 + ni * 16 + fr;
    float bv = bias ? bias[col] : 0.f;
    #pragma unroll
    for (int mi = 0; mi < 4; ++mi){
      #pragma unroll
      for (int i = 0; i < 4; ++i){
        int row = row0 + wm * 64 + mi * 16 + fq * 4 + i;
        if (row < M){
          float v = acc[mi][ni][i] + bv;
          if (Cb) Cb[(size_t)row * ldc + col] = f2bf(v);
          else    Cf[(size_t)row * ldc + col] = v;
        }
      }
    }
  }
}

// --------------------------- LayerNorm + SiLU ------------------------------
__global__ __launch_bounds__(256) void k_ln_silu(
    const float* __restrict__ in, const float* __restrict__ sc,
    const float* __restrict__ bb, u16* __restrict__ out)
{
  int e = blockIdx.x, t = threadIdx.x;
  float v = in[(size_t)e * 256 + t];
  float s1 = v, s2 = v * v;
  #pragma unroll
  for (int off = 32; off > 0; off >>= 1){
    s1 += __shfl_down(s1, off);
    s2 += __shfl_down(s2, off);
  }
  __shared__ float r1[4], r2[4];
  if ((t & 63) == 0){ r1[t >> 6] = s1; r2[t >> 6] = s2; }
  __syncthreads();
  float S1 = r1[0] + r1[1] + r1[2] + r1[3];
  float S2 = r2[0] + r2[1] + r2[2] + r2[3];
  float mu  = S1 * (1.f / 256.f);
  float var = S2 * (1.f / 256.f) - mu * mu;
  float nv = (v - mu) * rsqrtf(var + 1e-5f) * sc[t] + bb[t];
  out[(size_t)e * 256 + t] = f2bf(nv * sigm(nv));
}

// --------------------- Wigner forward (gather+scale) -----------------------
// j-blocked: 8 independent x-loads in flight, then 29x8 FMAs.
__global__ __launch_bounds__(256) void k_wig_fwd(
    const float* __restrict__ x, const int* __restrict__ eidx,
    const float* __restrict__ wig, const u16* __restrict__ xrad,
    u16* __restrict__ msgS, int e0)
{
  int el = blockIdx.x, c = threadIdx.x;
  int eg = e0 + el;
  int node = eidx[(c < 128 ? 0 : E_NUM) + eg];
  const float* xs = x + (size_t)node * 6272 + (c & 127);
  const float* w = wig + (size_t)eg * 1421;   // uniform per block -> s_loads
  float acc[29];
  #pragma unroll
  for (int m = 0; m < 29; ++m) acc[m] = 0.f;
  #pragma unroll
  for (int jb = 0; jb < 48; jb += 8){
    float xv[8];
    #pragma unroll
    for (int jj = 0; jj < 8; ++jj) xv[jj] = xs[(size_t)(jb + jj) * 128];
    #pragma unroll
    for (int m = 0; m < 29; ++m)
      #pragma unroll
      for (int jj = 0; jj < 8; ++jj)
        acc[m] = fmaf(w[m * 49 + jb + jj], xv[jj], acc[m]);
  }
  { float xl = xs[48 * 128];
    #pragma unroll
    for (int m = 0; m < 29; ++m) acc[m] = fmaf(w[m * 49 + 48], xl, acc[m]); }
  const u16* xr = xrad + (size_t)el * 4608 + c;
  u16* o = msgS + (size_t)el * 7424 + c;
  #pragma unroll
  for (int m = 0; m < 29; ++m){
    int rr = (m < 13) ? m : (m < 24 ? m - 6 : m - 11);
    o[m * 256] = f2bf(acc[m] * bf2f(xr[rr * 256]));
  }
}

// ------------------------ gate + recombine (conv1) -------------------------
__global__ __launch_bounds__(128) void k_gate(
    const u16* __restrict__ c1m0, const u16* __restrict__ y10, const u16* __restrict__ y11,
    const u16* __restrict__ y20, const u16* __restrict__ y21, u16* __restrict__ msg2)
{
  int e = blockIdx.x, c = threadIdx.x;
  __shared__ float g[768];
  const u16* gp = c1m0 + (size_t)e * 1664;
  for (int i = c; i < 768; i += 128) g[i] = sigm(bf2f(gp[i]));
  __syncthreads();
  const u16* x0 = gp + 768;
  u16* o = msg2 + (size_t)e * 3712;
  { float v = bf2f(x0[c]); o[c] = f2bf(v * sigm(v)); }
  #pragma unroll
  for (int r = 1; r < 7; ++r)
    o[r * 128 + c] = f2bf(bf2f(x0[r * 128 + c]) * g[(r - 1) * 128 + c]);
  const u16* a0 = y10 + (size_t)e * 1536;
  const u16* a1 = y11 + (size_t)e * 1536;
  #pragma unroll
  for (int k = 0; k < 6; ++k){
    float orr = bf2f(a0[k * 128 + c]) - bf2f(a1[768 + k * 128 + c]);
    float oii = bf2f(a1[k * 128 + c]) + bf2f(a0[768 + k * 128 + c]);
    float gv = g[k * 128 + c];
    o[(7 + k)  * 128 + c] = f2bf(orr * gv);
    o[(13 + k) * 128 + c] = f2bf(oii * gv);
  }
  const u16* b0 = y20 + (size_t)e * 1280;
  const u16* b1 = y21 + (size_t)e * 1280;
  #pragma unroll
  for (int k = 0; k < 5; ++k){
    float orr = bf2f(b0[k * 128 + c]) - bf2f(b1[640 + k * 128 + c]);
    float oii = bf2f(b1[k * 128 + c]) + bf2f(b0[640 + k * 128 + c]);
    float gv = g[(1 + k) * 128 + c];
    o[(19 + k) * 128 + c] = f2bf(orr * gv);
    o[(24 + k) * 128 + c] = f2bf(oii * gv);
  }
}

// --------------------- recombine2 + envelope (conv2) -----------------------
__global__ __launch_bounds__(128) void k_recomb2(
    const u16* __restrict__ m3x0, const u16* __restrict__ z10, const u16* __restrict__ z11,
    const u16* __restrict__ z20, const u16* __restrict__ z21, const float* __restrict__ env,
    u16* __restrict__ msg3)
{
  int e = blockIdx.x, c = threadIdx.x;
  float ev = env[e];
  const u16* x0 = m3x0 + (size_t)e * 896;
  u16* o = msg3 + (size_t)e * 3712;
  #pragma unroll
  for (int r = 0; r < 7; ++r) o[r * 128 + c] = f2bf(bf2f(x0[r * 128 + c]) * ev);
  const u16* a0 = z10 + (size_t)e * 1536;
  const u16* a1 = z11 + (size_t)e * 1536;
  #pragma unroll
  for (int k = 0; k < 6; ++k){
    float orr = bf2f(a0[k * 128 + c]) - bf2f(a1[768 + k * 128 + c]);
    float oii = bf2f(a1[k * 128 + c]) + bf2f(a0[768 + k * 128 + c]);
    o[(7 + k)  * 128 + c] = f2bf(orr * ev);
    o[(13 + k) * 128 + c] = f2bf(oii * ev);
  }
  const u16* b0 = z20 + (size_t)e * 1280;
  const u16* b1 = z21 + (size_t)e * 1280;
  #pragma unroll
  for (int k = 0; k < 5; ++k){
    float orr = bf2f(b0[k * 128 + c]) - bf2f(b1[640 + k * 128 + c]);
    float oii = bf2f(b1[k * 128 + c]) + bf2f(b0[640 + k * 128 + c]);
    o[(19 + k) * 128 + c] = f2bf(orr * ev);
    o[(24 + k) * 128 + c] = f2bf(oii * ev);
  }
}

// -------------------- Wigner inverse + scatter-add -------------------------
// 256 threads: c = t&127 channel, j-range split across t>>7.
__global__ __launch_bounds__(256) void k_wig_inv(
    const u16* __restrict__ msg3, const float* __restrict__ winv,
    const int* __restrict__ eidx, float* __restrict__ out, int e0)
{
  int el = blockIdx.x, t = threadIdx.x;
  int c = t & 127, jh = t >> 7;
  int eg = e0 + el;
  const u16* mp = msg3 + (size_t)el * 3712 + c;
  float vm[29];
  #pragma unroll
  for (int m = 0; m < 29; ++m) vm[m] = bf2f(mp[m * 128]);
  const float* w = winv + (size_t)eg * 1421;   // uniform -> s_loads
  int dst = eidx[E_NUM + eg];
  float* op = out + (size_t)dst * 6272 + c;
  int j0 = jh * 25, jend = jh ? 49 : 25;
  for (int j = j0; j < jend; ++j){
    float a = 0.f;
    #pragma unroll
    for (int m = 0; m < 29; ++m) a = fmaf(w[j * 29 + m], vm[m], a);
    atomicAdd(op + (size_t)j * 128, a);
  }
}

// ---------------------------------------------------------------------------
extern "C" void kernel_launch(void* const* d_in, const int* in_sizes, int n_in,
                              void* d_out, int out_size, void* d_ws, size_t ws_size,
                              hipStream_t stream)
{
  (void)in_sizes; (void)n_in;
  const float* x       = (const float*)d_in[0];
  const float* x_edge  = (const float*)d_in[1];
  const int*   eidx    = (const int*)d_in[3];
  const float* wig     = (const float*)d_in[4];
  const float* wig_inv = (const float*)d_in[5];
  const float* env     = (const float*)d_in[6];
  const float* rad_w0  = (const float*)d_in[7];
  const float* rad_b0  = (const float*)d_in[8];
  const float* ln0_s   = (const float*)d_in[9];
  const float* ln0_b   = (const float*)d_in[10];
  const float* rad_w1  = (const float*)d_in[11];
  const float* rad_b1  = (const float*)d_in[12];
  const float* ln1_s   = (const float*)d_in[13];
  const float* ln1_b   = (const float*)d_in[14];
  const float* rad_w2  = (const float*)d_in[15];
  const float* rad_b2  = (const float*)d_in[16];
  const float* c1w0    = (const float*)d_in[17];
  const float* c1b0    = (const float*)d_in[18];
  const float* c1w1    = (const float*)d_in[19];
  const float* c1w2    = (const float*)d_in[20];
  const float* c2w0    = (const float*)d_in[21];
  const float* c2b0    = (const float*)d_in[22];
  const float* c2w1    = (const float*)d_in[23];
  const float* c2w2    = (const float*)d_in[24];
  float* out = (float*)d_out;

  char* base = (char*)d_ws;
  size_t off = 0;
  auto alloc = [&](size_t bytes) -> char* {
    off = (off + 255) & ~(size_t)255;
    char* r = base + off;
    off += bytes;
    return r;
  };

  // ---- fixed area: transposed bf16 weights (~22.2 MB) ----
  u16* wtR0  = (u16*)alloc((size_t)256  * 128  * 2);
  u16* wtR1  = (u16*)alloc((size_t)256  * 256  * 2);
  u16* wtR2  = (u16*)alloc((size_t)4608 * 256  * 2);
  u16* wtC10 = (u16*)alloc((size_t)1664 * 1792 * 2);
  u16* wtC11 = (u16*)alloc((size_t)1536 * 1536 * 2);
  u16* wtC12 = (u16*)alloc((size_t)1280 * 1280 * 2);
  u16* wtC20 = (u16*)alloc((size_t)896  * 896  * 2);
  u16* wtC21 = (u16*)alloc((size_t)1536 * 768  * 2);
  u16* wtC22 = (u16*)alloc((size_t)1280 * 640  * 2);

  // ---- chunk size from remaining workspace (40,960 B per edge) ----
  size_t fixed_end = (off + 65536) & ~(size_t)65535;
  size_t avail = (ws_size > fixed_end + (1u << 20)) ? (ws_size - fixed_end - (1u << 20)) : 0;
  int CH = (int)(avail / 40960);
  if (CH > 5000) CH = 5000;
  CH &= ~63;
  if (CH < 64) CH = 64;

  off = fixed_end;
  const size_t C = (size_t)CH;
  u16*   xe   = (u16*)alloc(C * 128 * 2);
  float* tmp  = (float*)alloc(C * 256 * 4);
  u16*   h0   = (u16*)alloc(C * 256 * 2);
  u16*   h1   = (u16*)alloc(C * 256 * 2);
  u16* region1 = (u16*)alloc(C * 4608 * 2);   // xrad -> msg2
  u16* region2 = (u16*)alloc(C * 7424 * 2);   // msgS -> conv2 outs
  u16* region3 = (u16*)alloc(C * 7296 * 2);   // conv1 outs -> msg3
  u16* xrad = region1;
  u16* msg2 = region1;
  u16* msgS = region2;
  u16* m3x0 = region2;                 // (C,896)
  u16* z10  = region2 + C * 896;       // (C,1536)
  u16* z11  = region2 + C * 2432;      // (C,1536)
  u16* z20  = region2 + C * 3968;      // (C,1280)
  u16* z21  = region2 + C * 5248;      // (C,1280)
  u16* c1m0b = region3;                // (C,1664)
  u16* y10   = region3 + C * 1664;     // (C,1536)
  u16* y11   = region3 + C * 3200;     // (C,1536)
  u16* y20   = region3 + C * 4736;     // (C,1280)
  u16* y21   = region3 + C * 6016;     // (C,1280)
  u16* msg3  = region3;                // (C,3712)

  hipMemsetAsync(d_out, 0, (size_t)out_size * sizeof(float), stream);

  auto tw = [&](const float* in, u16* o, int K, int N){
    k_transpose_w<<<dim3(N / 32, K / 32), 256, 0, stream>>>(in, o, K, N);
  };
  tw(rad_w0, wtR0, 128, 256);
  tw(rad_w1, wtR1, 256, 256);
  tw(rad_w2, wtR2, 256, 4608);
  tw(c1w0, wtC10, 1792, 1664);
  tw(c1w1, wtC11, 1536, 1536);
  tw(c1w2, wtC12, 1280, 1280);
  tw(c2w0, wtC20, 896, 896);
  tw(c2w1, wtC21, 768, 1536);
  tw(c2w2, wtC22, 640, 1280);

  auto gemm = [&](const u16* A, int lda, const u16* B, const float* bias,
                  float* Cf, u16* Cb, int ldc, int M, int N, int K){
    k_gemm_bt<<<dim3(N / 128, (M + 127) / 128), 256, 0, stream>>>(
        A, lda, B, bias, Cf, Cb, ldc, M, N, K);
  };

  for (int e0 = 0; e0 < E_NUM; e0 += CH){
    int cm = E_NUM - e0 < CH ? E_NUM - e0 : CH;

    k_f2bf<<<(cm * 128 + 255) / 256, 256, 0, stream>>>(x_edge + (size_t)e0 * 128, xe, cm * 128);

    // radial MLP
    gemm(xe, 128, wtR0, rad_b0, tmp, nullptr, 256, cm, 256, 128);
    k_ln_silu<<<cm, 256, 0, stream>>>(tmp, ln0_s, ln0_b, h0);
    gemm(h0, 256, wtR1, rad_b1, tmp, nullptr, 256, cm, 256, 256);
    k_ln_silu<<<cm, 256, 0, stream>>>(tmp, ln1_s, ln1_b, h1);
    gemm(h1, 256, wtR2, rad_b2, nullptr, xrad, 4608, cm, 4608, 256);

    // wigner forward + gather + radial scale
    k_wig_fwd<<<cm, 256, 0, stream>>>(x, eidx, wig, xrad, msgS, e0);

    // conv1
    gemm(msgS,        7424, wtC10, c1b0,    nullptr, c1m0b, 1664, cm, 1664, 1792);
    gemm(msgS + 1792, 7424, wtC11, nullptr, nullptr, y10,  1536, cm, 1536, 1536);
    gemm(msgS + 3328, 7424, wtC11, nullptr, nullptr, y11,  1536, cm, 1536, 1536);
    gemm(msgS + 4864, 7424, wtC12, nullptr, nullptr, y20,  1280, cm, 1280, 1280);
    gemm(msgS + 6144, 7424, wtC12, nullptr, nullptr, y21,  1280, cm, 1280, 1280);

    k_gate<<<cm, 128, 0, stream>>>(c1m0b, y10, y11, y20, y21, msg2);

    // conv2
    gemm(msg2,        3712, wtC20, c2b0,    nullptr, m3x0, 896,  cm, 896,  896);
    gemm(msg2 + 896,  3712, wtC21, nullptr, nullptr, z10, 1536, cm, 1536, 768);
    gemm(msg2 + 1664, 3712, wtC21, nullptr, nullptr, z11, 1536, cm, 1536, 768);
    gemm(msg2 + 2432, 3712, wtC22, nullptr, nullptr, z20, 1280, cm, 1280, 640);
    gemm(msg2 + 3072, 3712, wtC22, nullptr, nullptr, z21, 1280, cm, 1280, 640);

    k_recomb2<<<cm, 128, 0, stream>>>(m3x0, z10, z11, z20, z21, env + e0, msg3);

    // wigner inverse + scatter
    k_wig_inv<<<cm, 256, 0, stream>>>(msg3, wig_inv, eidx, out, e0);
  }
}